// Round 20
// baseline (29.214 us; speedup 1.0000x reference)
//
#include <hip/hip_runtime.h>
#include <hip/hip_fp16.h>

// 5x5 median, reflect padding, NHWC f32 (16,384,384,3).
// R18 (25.3us): 4 cols/thread, two packed-f16 pipelines, float4 loads, RUN=6.
// R20 single change: RUN 6 -> 12 via a ROLLED 2-iteration loop over the
// 3-phase block (slot map slot(r)=(r-h0+2) mod 6 is period-6, so the phase
// code loops verbatim with hbase = h0 + 6*it). Rows sorted per output-row
// 1.67 -> 1.33 (-6% insts). R19 established issue-bound (coupling 0.6), so
// predicted ~ -4%. Waves 4752 -> 2376 (risk: latency exposure; R19 says low).

typedef __fp16 h2 __attribute__((ext_vector_type(2)));

__device__ __forceinline__ h2 h2min(h2 a, h2 b) { return __builtin_elementwise_min(a, b); }
__device__ __forceinline__ h2 h2max(h2 a, h2 b) { return __builtin_elementwise_max(a, b); }
__device__ __forceinline__ h2 pk2(float a, float b) { return __builtin_amdgcn_cvt_pkrtz(a, b); }

#define CAS2(a, b) do { h2 _t = h2min(a, b); (b) = h2max(a, b); (a) = _t; } while (0)

#define SORT5P(e0, e1, e2, e3, e4) do { \
  CAS2(e0, e1); CAS2(e3, e4); CAS2(e2, e4); CAS2(e2, e3); CAS2(e1, e4); \
  CAS2(e0, e3); CAS2(e0, e2); CAS2(e1, e3); CAS2(e1, e2); } while (0)

#define SORT4P(a, b, c, d) do { \
  CAS2(a, b); CAS2(c, d); CAS2(a, c); CAS2(b, d); CAS2(b, c); } while (0)

// ---- scalar f32 helpers (border path, exact) ----
#define MIN3(a, b, c) fminf(fminf(a, b), c)
#define MAX3(a, b, c) fmaxf(fmaxf(a, b), c)
#define MED3(a, b, c) __builtin_amdgcn_fmed3f((a), (b), (c))
#define CAS(a, b) do { float _t = fminf(a, b); (b) = fmaxf(a, b); (a) = _t; } while (0)
#define SORT3M(a, b, c) do { \
  float _lo = MIN3(a, b, c), _mi = MED3(a, b, c), _hi = MAX3(a, b, c); \
  (a) = _lo; (b) = _mi; (c) = _hi; } while (0)
#define SORT4M(a, b, c, d) do { \
  SORT3M(a, b, c); \
  float _n0 = fminf(a, d), _n1 = MED3(a, b, d), _n2 = MED3(b, c, d), _n3 = fmaxf(c, d); \
  (a) = _n0; (b) = _n1; (c) = _n2; (d) = _n3; } while (0)
#define SORT5M(a, b, c, d, e) do { \
  SORT4M(a, b, c, d); \
  float _m0 = fminf(a, e), _m1 = MED3(a, b, e), _m2 = MED3(b, c, e), \
        _m3 = MED3(c, d, e), _m4 = fmaxf(d, e); \
  (a) = _m0; (b) = _m1; (c) = _m2; (d) = _m3; (e) = _m4; } while (0)

__device__ __forceinline__ int reflect_idx(int v, int n) {
  v = v < 0 ? -v : v;
  v = v >= n ? 2 * n - 2 - v : v;
  return v;
}

#define SORT_TO(P, e0, e1, e2, e3, e4) do { \
  SORT5M(e0, e1, e2, e3, e4); \
  P##0 = e0; P##1 = e1; P##2 = e2; P##3 = e3; P##4 = e4; } while (0)

#define BANDSEL(dst) do { \
  CAS(B3, Cx3); CAS(A1, B1); CAS(A1, Cx1); \
  CAS(A2, B3); CAS(Cx2, D2); CAS(B3, D2); \
  CAS(B1, Cx1); CAS(D1, A2); CAS(B1, D1); \
  float s0=Cx1,s1=B2,s2=B3,s3=Cx2,s4=A2,s5=D1,s6=D3,s7=E1; \
  CAS(s0, s1); CAS(s2, s3); CAS(s4, s5); CAS(s6, s7); \
  CAS(s0, s2); CAS(s4, s6); CAS(s0, s4); \
  CAS(s1, s3); CAS(s5, s7); CAS(s3, s7); \
  float t0=s1,t1=s2,t2=s3,t3=s4,t4=s5,t5=s6,t6=E2; \
  CAS(t0, t1); CAS(t2, t3); CAS(t4, t5); \
  CAS(t0, t2); CAS(t0, t4); CAS(t0, t6); \
  CAS(t1, t3); CAS(t5, t6); CAS(t3, t6); \
  CAS(t1, t2); CAS(t3, t4); \
  CAS(t1, t3); CAS(t1, t5); \
  CAS(t2, t4); CAS(t4, t5); \
  dst = MED3(t2, t3, t4); \
} while (0)

#define MED25_PAIR(dA, dB, S0, S1, S2, S3, IA, IB) do { \
  float pp0=S0##0,qq0=S1##0,rr0=S2##0,ss0=S3##0; SORT4M(pp0,qq0,rr0,ss0); \
  float pp1=S0##1,qq1=S1##1,rr1=S2##1,ss1=S3##1; SORT4M(pp1,qq1,rr1,ss1); \
  float pp2=S0##2,qq2=S1##2,rr2=S2##2,ss2=S3##2; SORT4M(pp2,qq2,rr2,ss2); \
  float pp3=S0##3,qq3=S1##3,rr3=S2##3,ss3=S3##3; SORT4M(pp3,qq3,rr3,ss3); \
  float pp4=S0##4,qq4=S1##4,rr4=S2##4,ss4=S3##4; SORT4M(pp4,qq4,rr4,ss4); \
  { float D1 = MED3(rr0, ss0, IA##0), E1 = fmaxf(ss0, IA##0); \
    float Cx1 = MED3(qq1, rr1, IA##1), D2 = MED3(rr1, ss1, IA##1), E2 = fmaxf(ss1, IA##1); \
    float B1 = MED3(pp2, qq2, IA##2), Cx2 = MED3(qq2, rr2, IA##2), D3 = MED3(rr2, ss2, IA##2); \
    float A1 = fminf(pp3, IA##3), B2 = MED3(pp3, qq3, IA##3), Cx3 = MED3(qq3, rr3, IA##3); \
    float A2 = fminf(pp4, IA##4), B3 = MED3(pp4, qq4, IA##4); \
    BANDSEL(dA); } \
  { float D1 = MED3(rr0, ss0, IB##0), E1 = fmaxf(ss0, IB##0); \
    float Cx1 = MED3(qq1, rr1, IB##1), D2 = MED3(rr1, ss1, IB##1), E2 = fmaxf(ss1, IB##1); \
    float B1 = MED3(pp2, qq2, IB##2), Cx2 = MED3(qq2, rr2, IB##2), D3 = MED3(rr2, ss2, IB##2); \
    float A1 = fminf(pp3, IB##3), B2 = MED3(pp3, qq3, IB##3), Cx3 = MED3(qq3, rr3, IB##3); \
    float A2 = fminf(pp4, IB##4), B3 = MED3(pp4, qq4, IB##4); \
    BANDSEL(dB); } \
} while (0)

// ---- packed BANDSEL (liveness-optimized, validated R16-R19) ----
#define BANDSEL2(dst) do { \
  B3 = h2min(B3, Cx3); \
  CAS2(A1, B1); \
  Cx1 = h2max(A1, Cx1); \
  CAS2(A2, B3); \
  CAS2(Cx2, D2); \
  B3 = h2min(B3, D2); \
  CAS2(B1, Cx1); \
  CAS2(D1, A2); \
  D1 = h2max(B1, D1); \
  h2 s0=Cx1,s1=B2,s2=B3,s3=Cx2,s4=A2,s5=D1,s6=D3,s7=E1; \
  CAS2(s0, s1); CAS2(s2, s3); CAS2(s4, s5); CAS2(s6, s7); \
  CAS2(s0, s2); CAS2(s4, s6); \
  s4 = h2max(s0, s4); \
  CAS2(s1, s3); CAS2(s5, s7); \
  s3 = h2min(s3, s7); \
  h2 t0=s1,t1=s2,t2=s3,t3=s4,t4=s5,t5=s6,t6=E2; \
  CAS2(t0, t1); CAS2(t2, t3); CAS2(t4, t5); \
  CAS2(t0, t2); CAS2(t0, t4); \
  t6 = h2max(t0, t6); \
  CAS2(t1, t3); CAS2(t5, t6); \
  t3 = h2min(t3, t6); \
  CAS2(t1, t2); CAS2(t3, t4); \
  CAS2(t1, t3); \
  t5 = h2max(t1, t5); \
  CAS2(t2, t4); \
  t4 = h2min(t4, t5); \
  CAS2(t2, t3); \
  dst = h2max(t2, h2min(t3, t4)); \
} while (0)

#define MED25P(dA, dB, S0, S1, S2, S3, IA, IB) do { \
  h2 pp0=S0##0,qq0=S1##0,rr0=S2##0,ss0=S3##0; SORT4P(pp0,qq0,rr0,ss0); \
  h2 pp1=S0##1,qq1=S1##1,rr1=S2##1,ss1=S3##1; SORT4P(pp1,qq1,rr1,ss1); \
  h2 pp2=S0##2,qq2=S1##2,rr2=S2##2,ss2=S3##2; SORT4P(pp2,qq2,rr2,ss2); \
  h2 pp3=S0##3,qq3=S1##3,rr3=S2##3,ss3=S3##3; SORT4P(pp3,qq3,rr3,ss3); \
  h2 pp4=S0##4,qq4=S1##4,rr4=S2##4,ss4=S3##4; SORT4P(pp4,qq4,rr4,ss4); \
  { h2 D1 = h2max(rr0, h2min(ss0, IA##0)), E1 = h2max(ss0, IA##0); \
    h2 Cx1 = h2max(qq1, h2min(rr1, IA##1)), D2 = h2max(rr1, h2min(ss1, IA##1)), E2 = h2max(ss1, IA##1); \
    h2 B1 = h2max(pp2, h2min(qq2, IA##2)), Cx2 = h2max(qq2, h2min(rr2, IA##2)), D3 = h2max(rr2, h2min(ss2, IA##2)); \
    h2 A1 = h2min(pp3, IA##3), B2 = h2max(pp3, h2min(qq3, IA##3)), Cx3 = h2max(qq3, h2min(rr3, IA##3)); \
    h2 A2 = h2min(pp4, IA##4), B3 = h2max(pp4, h2min(qq4, IA##4)); \
    BANDSEL2(dA); } \
  { h2 D1 = h2max(rr0, h2min(ss0, IB##0)), E1 = h2max(ss0, IB##0); \
    h2 Cx1 = h2max(qq1, h2min(rr1, IB##1)), D2 = h2max(rr1, h2min(ss1, IB##1)), E2 = h2max(ss1, IB##1); \
    h2 B1 = h2max(pp2, h2min(qq2, IB##2)), Cx2 = h2max(qq2, h2min(rr2, IB##2)), D3 = h2max(rr2, h2min(ss2, IB##2)); \
    h2 A1 = h2min(pp3, IB##3), B2 = h2max(pp3, h2min(qq3, IB##3)), Cx3 = h2max(qq3, h2min(rr3, IB##3)); \
    h2 A2 = h2min(pp4, IB##4), B3 = h2max(pp4, h2min(qq4, IB##4)); \
    BANDSEL2(dB); } \
} while (0)

constexpr int RUN = 12;
constexpr int ITERS = RUN / 6;           // 2 iterations of the period-6 phase block
constexpr int Bn = 16, Hn = 384, Wn = 384, Cn = 3;
constexpr int WC = Wn * Cn;              // 1152
constexpr int HB = Hn / RUN;             // 32
constexpr int NG_I = 285;                // 4-col groups: f = 6 + 4*gi
constexpr int N_INT = Bn * HB * NG_I;    // 145920 = 2280 * 64
constexpr int N_BND = Bn * HB * 12;      // 6144   = 96 * 64
constexpr int BLOCK = 64;

// Load row RR: 16 floats (f-6..f+9) as 4 float4 (16B-aligned: f-6 = 4*gi).
#define LOADROW4(W0,W1,W2,W3, RR) do { \
  const float4* rp = reinterpret_cast<const float4*>(xb + reflect_idx((RR), Hn) * WC); \
  W0=rp[0]; W1=rp[1]; W2=rp[2]; W3=rp[3]; } while (0)

// Pack+sort row into pipeline P (cols f,f+1) and Q (cols f+2,f+3).
#define SORTROW2(W0,W1,W2,W3, P, Q) do { \
  h2 e0 = pk2(W0.x, W0.y), e1 = pk2(W0.w, W1.x), e2 = pk2(W1.z, W1.w), \
     e3 = pk2(W2.y, W2.z), e4 = pk2(W3.x, W3.y); \
  h2 g0 = pk2(W0.z, W0.w), g1 = pk2(W1.y, W1.z), g2 = pk2(W2.x, W2.y), \
     g3 = pk2(W2.w, W3.x), g4 = pk2(W3.z, W3.w); \
  SORT5P(e0, e1, e2, e3, e4); \
  SORT5P(g0, g1, g2, g3, g4); \
  P##0 = e0; P##1 = e1; P##2 = e2; P##3 = e3; P##4 = e4; \
  Q##0 = g0; Q##1 = g1; Q##2 = g2; Q##3 = g3; Q##4 = g4; } while (0)

#define STORE4(off, pA, qA) do { \
  float2 w1; w1.x = (float)pA[0]; w1.y = (float)pA[1]; \
  float2 w2; w2.x = (float)qA[0]; w2.y = (float)qA[1]; \
  *reinterpret_cast<float2*>(out + (off))     = w1; \
  *reinterpret_cast<float2*>(out + (off) + 2) = w2; } while (0)

__global__ __launch_bounds__(BLOCK) void median5x5_kernel(
    const float* __restrict__ x, float* __restrict__ out) {
  int t = blockIdx.x * blockDim.x + threadIdx.x;

  if (t < N_INT) {
    // ---------------- interior: 4 cols, two packed pipelines ----------------
    int gi = t % NG_I;
    int rest = t / NG_I;
    int hb = rest % HB;
    int b = rest / HB;
    int h0 = hb * RUN;
    int f = 6 + 4 * gi;

    const float* xb = x + b * Hn * WC + (f - 6);

    // two 6-slot rings of packed sorted 5-windows; slot(r) = (r-h0+2) mod 6
    h2 P00,P01,P02,P03,P04, P10,P11,P12,P13,P14, P20,P21,P22,P23,P24,
       P30,P31,P32,P33,P34, P40,P41,P42,P43,P44, P50,P51,P52,P53,P54;
    h2 Q00,Q01,Q02,Q03,Q04, Q10,Q11,Q12,Q13,Q14, Q20,Q21,Q22,Q23,Q24,
       Q30,Q31,Q32,Q33,Q34, Q40,Q41,Q42,Q43,Q44, Q50,Q51,Q52,Q53,Q54;

    float4 v0,v1,v2,v3;   // prefetch row A
    float4 u0,u1,u2,u3;   // prefetch row B

    LOADROW4(v0,v1,v2,v3, h0 - 2); SORTROW2(v0,v1,v2,v3, P0, Q0);
    LOADROW4(v0,v1,v2,v3, h0 - 1); SORTROW2(v0,v1,v2,v3, P1, Q1);
    LOADROW4(v0,v1,v2,v3, h0    ); SORTROW2(v0,v1,v2,v3, P2, Q2);
    LOADROW4(v0,v1,v2,v3, h0 + 1); SORTROW2(v0,v1,v2,v3, P3, Q3);

    LOADROW4(v0,v1,v2,v3, h0 + 2);
    LOADROW4(u0,u1,u2,u3, h0 + 3);

    int orow = (b * Hn + h0) * WC + f;

#pragma unroll 1
    for (int it = 0; it < ITERS; ++it) {
      int hbase = h0 + 6 * it;

      // ---- phase 0: outputs hbase, hbase+1 ----
      SORTROW2(v0,v1,v2,v3, P4, Q4);           // row hbase+2 -> slot 4
      SORTROW2(u0,u1,u2,u3, P5, Q5);           // row hbase+3 -> slot 5
      LOADROW4(v0,v1,v2,v3, hbase + 4);
      LOADROW4(u0,u1,u2,u3, hbase + 5);
      {
        h2 pA, pB, qA, qB;
        MED25P(pA, pB, P1, P2, P3, P4, P0, P5);
        MED25P(qA, qB, Q1, Q2, Q3, Q4, Q0, Q5);
        STORE4(orow,          pA, qA);
        STORE4(orow + 1 * WC, pB, qB);
      }

      // ---- phase 1: outputs hbase+2, hbase+3 ----
      SORTROW2(v0,v1,v2,v3, P0, Q0);           // row hbase+4 -> slot 0
      SORTROW2(u0,u1,u2,u3, P1, Q1);           // row hbase+5 -> slot 1
      LOADROW4(v0,v1,v2,v3, hbase + 6);
      LOADROW4(u0,u1,u2,u3, hbase + 7);
      {
        h2 pA, pB, qA, qB;
        MED25P(pA, pB, P3, P4, P5, P0, P2, P1);
        MED25P(qA, qB, Q3, Q4, Q5, Q0, Q2, Q1);
        STORE4(orow + 2 * WC, pA, qA);
        STORE4(orow + 3 * WC, pB, qB);
      }

      // ---- phase 2: outputs hbase+4, hbase+5 ----
      SORTROW2(v0,v1,v2,v3, P2, Q2);           // row hbase+6 -> slot 2
      SORTROW2(u0,u1,u2,u3, P3, Q3);           // row hbase+7 -> slot 3
      if (it + 1 < ITERS) {                     // prefetch next iteration's rows
        LOADROW4(v0,v1,v2,v3, hbase + 8);
        LOADROW4(u0,u1,u2,u3, hbase + 9);
      }
      {
        h2 pA, pB, qA, qB;
        MED25P(pA, pB, P5, P0, P1, P2, P4, P3);
        MED25P(qA, qB, Q5, Q0, Q1, Q2, Q4, Q3);
        STORE4(orow + 4 * WC, pA, qA);
        STORE4(orow + 5 * WC, pB, qB);
      }

      orow += 6 * WC;
    }
  } else {
    // ---------------- border columns: exact scalar f32 path ----------------
    int u = t - N_INT;
    int col = u % 12;
    int rest = u / 12;
    int hb = rest % HB;
    int b = rest / HB;
    int h0 = hb * RUN;
    int f = col < 6 ? col : (WC - 12 + col);   // 0..5 or 1146..1151
    int w = f / 3, c = f % 3;

    int o0 = reflect_idx(w - 2, Wn) * 3 + c;
    int o1 = reflect_idx(w - 1, Wn) * 3 + c;
    int o2 = w * 3 + c;
    int o3 = reflect_idx(w + 1, Wn) * 3 + c;
    int o4 = reflect_idx(w + 2, Wn) * 3 + c;

    const float* xb = x + b * Hn * WC;

    float a00,a01,a02,a03,a04, a10,a11,a12,a13,a14, a20,a21,a22,a23,a24,
          a30,a31,a32,a33,a34, a40,a41,a42,a43,a44, a50,a51,a52,a53,a54;

#define BLOAD_SORT(RR, AN) do { \
    const float* rp = xb + reflect_idx((RR), Hn) * WC; \
    float e0=rp[o0], e1=rp[o1], e2=rp[o2], e3=rp[o3], e4=rp[o4]; \
    SORT_TO(AN, e0, e1, e2, e3, e4); } while (0)

    BLOAD_SORT(h0 - 2, a0); BLOAD_SORT(h0 - 1, a1);
    BLOAD_SORT(h0    , a2); BLOAD_SORT(h0 + 1, a3);

    int orow = (b * Hn + h0) * WC + f;

#pragma unroll 1
    for (int it = 0; it < ITERS; ++it) {
      int hbase = h0 + 6 * it;

      BLOAD_SORT(hbase + 2, a4); BLOAD_SORT(hbase + 3, a5);
      {
        float oA, oB;
        MED25_PAIR(oA, oB, a1, a2, a3, a4, a0, a5);
        out[orow         ] = oA;
        out[orow + 1 * WC] = oB;
      }
      BLOAD_SORT(hbase + 4, a0); BLOAD_SORT(hbase + 5, a1);
      {
        float oA, oB;
        MED25_PAIR(oA, oB, a3, a4, a5, a0, a2, a1);
        out[orow + 2 * WC] = oA;
        out[orow + 3 * WC] = oB;
      }
      BLOAD_SORT(hbase + 6, a2); BLOAD_SORT(hbase + 7, a3);
      {
        float oA, oB;
        MED25_PAIR(oA, oB, a5, a0, a1, a2, a4, a3);
        out[orow + 4 * WC] = oA;
        out[orow + 5 * WC] = oB;
      }

      orow += 6 * WC;
    }
  }
}

extern "C" void kernel_launch(void* const* d_in, const int* in_sizes, int n_in,
                              void* d_out, int out_size, void* d_ws, size_t ws_size,
                              hipStream_t stream) {
  const float* x = (const float*)d_in[0];
  float* out = (float*)d_out;
  int total_threads = N_INT + N_BND;        // 152064 = 2376 * 64 exactly
  int grid = total_threads / BLOCK;         // 2376
  median5x5_kernel<<<grid, BLOCK, 0, stream>>>(x, out);
}

// Round 21
// 25.108 us; speedup vs baseline: 1.1635x; 1.1635x over previous
//
#include <hip/hip_runtime.h>
#include <hip/hip_fp16.h>

// 5x5 median, reflect padding, NHWC f32 (16,384,384,3).
// R21 = R18 (bracketed optimum: RUN=6, 4 cols/thread, two packed-f16
// pipelines, float4 loads, BLOCK=64; RUN=4 -> 26.1, RUN=6 -> 25.3,
// RUN=12 -> 29.2) + pipelined PROLOGUE: interleave the 4 prologue
// loads/sorts via the existing v/u buffers so each load has a ~40-inst
// sort between issue and wait (R18 prologue was strictly serial).

typedef __fp16 h2 __attribute__((ext_vector_type(2)));

__device__ __forceinline__ h2 h2min(h2 a, h2 b) { return __builtin_elementwise_min(a, b); }
__device__ __forceinline__ h2 h2max(h2 a, h2 b) { return __builtin_elementwise_max(a, b); }
__device__ __forceinline__ h2 pk2(float a, float b) { return __builtin_amdgcn_cvt_pkrtz(a, b); }

#define CAS2(a, b) do { h2 _t = h2min(a, b); (b) = h2max(a, b); (a) = _t; } while (0)

#define SORT5P(e0, e1, e2, e3, e4) do { \
  CAS2(e0, e1); CAS2(e3, e4); CAS2(e2, e4); CAS2(e2, e3); CAS2(e1, e4); \
  CAS2(e0, e3); CAS2(e0, e2); CAS2(e1, e3); CAS2(e1, e2); } while (0)

#define SORT4P(a, b, c, d) do { \
  CAS2(a, b); CAS2(c, d); CAS2(a, c); CAS2(b, d); CAS2(b, c); } while (0)

// ---- scalar f32 helpers (border path, exact) ----
#define MIN3(a, b, c) fminf(fminf(a, b), c)
#define MAX3(a, b, c) fmaxf(fmaxf(a, b), c)
#define MED3(a, b, c) __builtin_amdgcn_fmed3f((a), (b), (c))
#define CAS(a, b) do { float _t = fminf(a, b); (b) = fmaxf(a, b); (a) = _t; } while (0)
#define SORT3M(a, b, c) do { \
  float _lo = MIN3(a, b, c), _mi = MED3(a, b, c), _hi = MAX3(a, b, c); \
  (a) = _lo; (b) = _mi; (c) = _hi; } while (0)
#define SORT4M(a, b, c, d) do { \
  SORT3M(a, b, c); \
  float _n0 = fminf(a, d), _n1 = MED3(a, b, d), _n2 = MED3(b, c, d), _n3 = fmaxf(c, d); \
  (a) = _n0; (b) = _n1; (c) = _n2; (d) = _n3; } while (0)
#define SORT5M(a, b, c, d, e) do { \
  SORT4M(a, b, c, d); \
  float _m0 = fminf(a, e), _m1 = MED3(a, b, e), _m2 = MED3(b, c, e), \
        _m3 = MED3(c, d, e), _m4 = fmaxf(d, e); \
  (a) = _m0; (b) = _m1; (c) = _m2; (d) = _m3; (e) = _m4; } while (0)

__device__ __forceinline__ int reflect_idx(int v, int n) {
  v = v < 0 ? -v : v;
  v = v >= n ? 2 * n - 2 - v : v;
  return v;
}

#define SORT_TO(P, e0, e1, e2, e3, e4) do { \
  SORT5M(e0, e1, e2, e3, e4); \
  P##0 = e0; P##1 = e1; P##2 = e2; P##3 = e3; P##4 = e4; } while (0)

#define BANDSEL(dst) do { \
  CAS(B3, Cx3); CAS(A1, B1); CAS(A1, Cx1); \
  CAS(A2, B3); CAS(Cx2, D2); CAS(B3, D2); \
  CAS(B1, Cx1); CAS(D1, A2); CAS(B1, D1); \
  float s0=Cx1,s1=B2,s2=B3,s3=Cx2,s4=A2,s5=D1,s6=D3,s7=E1; \
  CAS(s0, s1); CAS(s2, s3); CAS(s4, s5); CAS(s6, s7); \
  CAS(s0, s2); CAS(s4, s6); CAS(s0, s4); \
  CAS(s1, s3); CAS(s5, s7); CAS(s3, s7); \
  float t0=s1,t1=s2,t2=s3,t3=s4,t4=s5,t5=s6,t6=E2; \
  CAS(t0, t1); CAS(t2, t3); CAS(t4, t5); \
  CAS(t0, t2); CAS(t0, t4); CAS(t0, t6); \
  CAS(t1, t3); CAS(t5, t6); CAS(t3, t6); \
  CAS(t1, t2); CAS(t3, t4); \
  CAS(t1, t3); CAS(t1, t5); \
  CAS(t2, t4); CAS(t4, t5); \
  dst = MED3(t2, t3, t4); \
} while (0)

#define MED25_PAIR(dA, dB, S0, S1, S2, S3, IA, IB) do { \
  float pp0=S0##0,qq0=S1##0,rr0=S2##0,ss0=S3##0; SORT4M(pp0,qq0,rr0,ss0); \
  float pp1=S0##1,qq1=S1##1,rr1=S2##1,ss1=S3##1; SORT4M(pp1,qq1,rr1,ss1); \
  float pp2=S0##2,qq2=S1##2,rr2=S2##2,ss2=S3##2; SORT4M(pp2,qq2,rr2,ss2); \
  float pp3=S0##3,qq3=S1##3,rr3=S2##3,ss3=S3##3; SORT4M(pp3,qq3,rr3,ss3); \
  float pp4=S0##4,qq4=S1##4,rr4=S2##4,ss4=S3##4; SORT4M(pp4,qq4,rr4,ss4); \
  { float D1 = MED3(rr0, ss0, IA##0), E1 = fmaxf(ss0, IA##0); \
    float Cx1 = MED3(qq1, rr1, IA##1), D2 = MED3(rr1, ss1, IA##1), E2 = fmaxf(ss1, IA##1); \
    float B1 = MED3(pp2, qq2, IA##2), Cx2 = MED3(qq2, rr2, IA##2), D3 = MED3(rr2, ss2, IA##2); \
    float A1 = fminf(pp3, IA##3), B2 = MED3(pp3, qq3, IA##3), Cx3 = MED3(qq3, rr3, IA##3); \
    float A2 = fminf(pp4, IA##4), B3 = MED3(pp4, qq4, IA##4); \
    BANDSEL(dA); } \
  { float D1 = MED3(rr0, ss0, IB##0), E1 = fmaxf(ss0, IB##0); \
    float Cx1 = MED3(qq1, rr1, IB##1), D2 = MED3(rr1, ss1, IB##1), E2 = fmaxf(ss1, IB##1); \
    float B1 = MED3(pp2, qq2, IB##2), Cx2 = MED3(qq2, rr2, IB##2), D3 = MED3(rr2, ss2, IB##2); \
    float A1 = fminf(pp3, IB##3), B2 = MED3(pp3, qq3, IB##3), Cx3 = MED3(qq3, rr3, IB##3); \
    float A2 = fminf(pp4, IB##4), B3 = MED3(pp4, qq4, IB##4); \
    BANDSEL(dB); } \
} while (0)

// ---- packed BANDSEL (liveness-optimized, validated R16-R20) ----
#define BANDSEL2(dst) do { \
  B3 = h2min(B3, Cx3); \
  CAS2(A1, B1); \
  Cx1 = h2max(A1, Cx1); \
  CAS2(A2, B3); \
  CAS2(Cx2, D2); \
  B3 = h2min(B3, D2); \
  CAS2(B1, Cx1); \
  CAS2(D1, A2); \
  D1 = h2max(B1, D1); \
  h2 s0=Cx1,s1=B2,s2=B3,s3=Cx2,s4=A2,s5=D1,s6=D3,s7=E1; \
  CAS2(s0, s1); CAS2(s2, s3); CAS2(s4, s5); CAS2(s6, s7); \
  CAS2(s0, s2); CAS2(s4, s6); \
  s4 = h2max(s0, s4); \
  CAS2(s1, s3); CAS2(s5, s7); \
  s3 = h2min(s3, s7); \
  h2 t0=s1,t1=s2,t2=s3,t3=s4,t4=s5,t5=s6,t6=E2; \
  CAS2(t0, t1); CAS2(t2, t3); CAS2(t4, t5); \
  CAS2(t0, t2); CAS2(t0, t4); \
  t6 = h2max(t0, t6); \
  CAS2(t1, t3); CAS2(t5, t6); \
  t3 = h2min(t3, t6); \
  CAS2(t1, t2); CAS2(t3, t4); \
  CAS2(t1, t3); \
  t5 = h2max(t1, t5); \
  CAS2(t2, t4); \
  t4 = h2min(t4, t5); \
  CAS2(t2, t3); \
  dst = h2max(t2, h2min(t3, t4)); \
} while (0)

#define MED25P(dA, dB, S0, S1, S2, S3, IA, IB) do { \
  h2 pp0=S0##0,qq0=S1##0,rr0=S2##0,ss0=S3##0; SORT4P(pp0,qq0,rr0,ss0); \
  h2 pp1=S0##1,qq1=S1##1,rr1=S2##1,ss1=S3##1; SORT4P(pp1,qq1,rr1,ss1); \
  h2 pp2=S0##2,qq2=S1##2,rr2=S2##2,ss2=S3##2; SORT4P(pp2,qq2,rr2,ss2); \
  h2 pp3=S0##3,qq3=S1##3,rr3=S2##3,ss3=S3##3; SORT4P(pp3,qq3,rr3,ss3); \
  h2 pp4=S0##4,qq4=S1##4,rr4=S2##4,ss4=S3##4; SORT4P(pp4,qq4,rr4,ss4); \
  { h2 D1 = h2max(rr0, h2min(ss0, IA##0)), E1 = h2max(ss0, IA##0); \
    h2 Cx1 = h2max(qq1, h2min(rr1, IA##1)), D2 = h2max(rr1, h2min(ss1, IA##1)), E2 = h2max(ss1, IA##1); \
    h2 B1 = h2max(pp2, h2min(qq2, IA##2)), Cx2 = h2max(qq2, h2min(rr2, IA##2)), D3 = h2max(rr2, h2min(ss2, IA##2)); \
    h2 A1 = h2min(pp3, IA##3), B2 = h2max(pp3, h2min(qq3, IA##3)), Cx3 = h2max(qq3, h2min(rr3, IA##3)); \
    h2 A2 = h2min(pp4, IA##4), B3 = h2max(pp4, h2min(qq4, IA##4)); \
    BANDSEL2(dA); } \
  { h2 D1 = h2max(rr0, h2min(ss0, IB##0)), E1 = h2max(ss0, IB##0); \
    h2 Cx1 = h2max(qq1, h2min(rr1, IB##1)), D2 = h2max(rr1, h2min(ss1, IB##1)), E2 = h2max(ss1, IB##1); \
    h2 B1 = h2max(pp2, h2min(qq2, IB##2)), Cx2 = h2max(qq2, h2min(rr2, IB##2)), D3 = h2max(rr2, h2min(ss2, IB##2)); \
    h2 A1 = h2min(pp3, IB##3), B2 = h2max(pp3, h2min(qq3, IB##3)), Cx3 = h2max(qq3, h2min(rr3, IB##3)); \
    h2 A2 = h2min(pp4, IB##4), B3 = h2max(pp4, h2min(qq4, IB##4)); \
    BANDSEL2(dB); } \
} while (0)

constexpr int RUN = 6;
constexpr int Bn = 16, Hn = 384, Wn = 384, Cn = 3;
constexpr int WC = Wn * Cn;              // 1152
constexpr int HB = Hn / RUN;             // 64
constexpr int NG_I = 285;                // 4-col groups: f = 6 + 4*gi
constexpr int N_INT = Bn * HB * NG_I;    // 291840 = 4560 * 64
constexpr int N_BND = Bn * HB * 12;      // 12288  = 192 * 64
constexpr int BLOCK = 64;

// Load row RR: 16 floats (f-6..f+9) as 4 float4 (16B-aligned: f-6 = 4*gi).
#define LOADROW4(W0,W1,W2,W3, RR) do { \
  const float4* rp = reinterpret_cast<const float4*>(xb + reflect_idx((RR), Hn) * WC); \
  W0=rp[0]; W1=rp[1]; W2=rp[2]; W3=rp[3]; } while (0)

// Pack+sort row into pipeline P (cols f,f+1) and Q (cols f+2,f+3).
#define SORTROW2(W0,W1,W2,W3, P, Q) do { \
  h2 e0 = pk2(W0.x, W0.y), e1 = pk2(W0.w, W1.x), e2 = pk2(W1.z, W1.w), \
     e3 = pk2(W2.y, W2.z), e4 = pk2(W3.x, W3.y); \
  h2 g0 = pk2(W0.z, W0.w), g1 = pk2(W1.y, W1.z), g2 = pk2(W2.x, W2.y), \
     g3 = pk2(W2.w, W3.x), g4 = pk2(W3.z, W3.w); \
  SORT5P(e0, e1, e2, e3, e4); \
  SORT5P(g0, g1, g2, g3, g4); \
  P##0 = e0; P##1 = e1; P##2 = e2; P##3 = e3; P##4 = e4; \
  Q##0 = g0; Q##1 = g1; Q##2 = g2; Q##3 = g3; Q##4 = g4; } while (0)

#define STORE4(off, pA, qA) do { \
  float2 w1; w1.x = (float)pA[0]; w1.y = (float)pA[1]; \
  float2 w2; w2.x = (float)qA[0]; w2.y = (float)qA[1]; \
  *reinterpret_cast<float2*>(out + (off))     = w1; \
  *reinterpret_cast<float2*>(out + (off) + 2) = w2; } while (0)

__global__ __launch_bounds__(BLOCK) void median5x5_kernel(
    const float* __restrict__ x, float* __restrict__ out) {
  int t = blockIdx.x * blockDim.x + threadIdx.x;

  if (t < N_INT) {
    // ---------------- interior: 4 cols, two packed pipelines ----------------
    int gi = t % NG_I;
    int rest = t / NG_I;
    int hb = rest % HB;
    int b = rest / HB;
    int h0 = hb * RUN;
    int f = 6 + 4 * gi;

    const float* xb = x + b * Hn * WC + (f - 6);

    // two 6-slot rings of packed sorted 5-windows; slot(r) = (r-h0+2) mod 6
    h2 P00,P01,P02,P03,P04, P10,P11,P12,P13,P14, P20,P21,P22,P23,P24,
       P30,P31,P32,P33,P34, P40,P41,P42,P43,P44, P50,P51,P52,P53,P54;
    h2 Q00,Q01,Q02,Q03,Q04, Q10,Q11,Q12,Q13,Q14, Q20,Q21,Q22,Q23,Q24,
       Q30,Q31,Q32,Q33,Q34, Q40,Q41,Q42,Q43,Q44, Q50,Q51,Q52,Q53,Q54;

    float4 v0,v1,v2,v3;   // buffer A
    float4 u0,u1,u2,u3;   // buffer B

    // pipelined prologue: always one load in flight behind each sort
    LOADROW4(v0,v1,v2,v3, h0 - 2);
    LOADROW4(u0,u1,u2,u3, h0 - 1);
    SORTROW2(v0,v1,v2,v3, P0, Q0);
    LOADROW4(v0,v1,v2,v3, h0    );
    SORTROW2(u0,u1,u2,u3, P1, Q1);
    LOADROW4(u0,u1,u2,u3, h0 + 1);
    SORTROW2(v0,v1,v2,v3, P2, Q2);
    LOADROW4(v0,v1,v2,v3, h0 + 2);     // prefetch phase-0 row A
    SORTROW2(u0,u1,u2,u3, P3, Q3);
    LOADROW4(u0,u1,u2,u3, h0 + 3);     // prefetch phase-0 row B

    int orow = (b * Hn + h0) * WC + f;

    // ---- phase 0: outputs h0, h0+1 ----
    SORTROW2(v0,v1,v2,v3, P4, Q4);           // row h0+2 -> slot 4
    SORTROW2(u0,u1,u2,u3, P5, Q5);           // row h0+3 -> slot 5
    LOADROW4(v0,v1,v2,v3, h0 + 4);
    LOADROW4(u0,u1,u2,u3, h0 + 5);
    {
      h2 pA, pB, qA, qB;
      MED25P(pA, pB, P1, P2, P3, P4, P0, P5);
      MED25P(qA, qB, Q1, Q2, Q3, Q4, Q0, Q5);
      STORE4(orow,          pA, qA);
      STORE4(orow + 1 * WC, pB, qB);
    }

    // ---- phase 1: outputs h0+2, h0+3 ----
    SORTROW2(v0,v1,v2,v3, P0, Q0);           // row h0+4 -> slot 0
    SORTROW2(u0,u1,u2,u3, P1, Q1);           // row h0+5 -> slot 1
    LOADROW4(v0,v1,v2,v3, h0 + 6);
    LOADROW4(u0,u1,u2,u3, h0 + 7);
    {
      h2 pA, pB, qA, qB;
      MED25P(pA, pB, P3, P4, P5, P0, P2, P1);
      MED25P(qA, qB, Q3, Q4, Q5, Q0, Q2, Q1);
      STORE4(orow + 2 * WC, pA, qA);
      STORE4(orow + 3 * WC, pB, qB);
    }

    // ---- phase 2: outputs h0+4, h0+5 ----
    SORTROW2(v0,v1,v2,v3, P2, Q2);           // row h0+6 -> slot 2
    SORTROW2(u0,u1,u2,u3, P3, Q3);           // row h0+7 -> slot 3
    {
      h2 pA, pB, qA, qB;
      MED25P(pA, pB, P5, P0, P1, P2, P4, P3);
      MED25P(qA, qB, Q5, Q0, Q1, Q2, Q4, Q3);
      STORE4(orow + 4 * WC, pA, qA);
      STORE4(orow + 5 * WC, pB, qB);
    }
  } else {
    // ---------------- border columns: exact scalar f32 path ----------------
    int u = t - N_INT;
    int col = u % 12;
    int rest = u / 12;
    int hb = rest % HB;
    int b = rest / HB;
    int h0 = hb * RUN;
    int f = col < 6 ? col : (WC - 12 + col);   // 0..5 or 1146..1151
    int w = f / 3, c = f % 3;

    int o0 = reflect_idx(w - 2, Wn) * 3 + c;
    int o1 = reflect_idx(w - 1, Wn) * 3 + c;
    int o2 = w * 3 + c;
    int o3 = reflect_idx(w + 1, Wn) * 3 + c;
    int o4 = reflect_idx(w + 2, Wn) * 3 + c;

    const float* xb = x + b * Hn * WC;

    float a00,a01,a02,a03,a04, a10,a11,a12,a13,a14, a20,a21,a22,a23,a24,
          a30,a31,a32,a33,a34, a40,a41,a42,a43,a44, a50,a51,a52,a53,a54;

#define BLOAD_SORT(RR, AN) do { \
    const float* rp = xb + reflect_idx((RR), Hn) * WC; \
    float e0=rp[o0], e1=rp[o1], e2=rp[o2], e3=rp[o3], e4=rp[o4]; \
    SORT_TO(AN, e0, e1, e2, e3, e4); } while (0)

    BLOAD_SORT(h0 - 2, a0); BLOAD_SORT(h0 - 1, a1);
    BLOAD_SORT(h0    , a2); BLOAD_SORT(h0 + 1, a3);

    int orow = (b * Hn + h0) * WC + f;

    BLOAD_SORT(h0 + 2, a4); BLOAD_SORT(h0 + 3, a5);
    {
      float oA, oB;
      MED25_PAIR(oA, oB, a1, a2, a3, a4, a0, a5);
      out[orow         ] = oA;
      out[orow + 1 * WC] = oB;
    }
    BLOAD_SORT(h0 + 4, a0); BLOAD_SORT(h0 + 5, a1);
    {
      float oA, oB;
      MED25_PAIR(oA, oB, a3, a4, a5, a0, a2, a1);
      out[orow + 2 * WC] = oA;
      out[orow + 3 * WC] = oB;
    }
    BLOAD_SORT(h0 + 6, a2); BLOAD_SORT(h0 + 7, a3);
    {
      float oA, oB;
      MED25_PAIR(oA, oB, a5, a0, a1, a2, a4, a3);
      out[orow + 4 * WC] = oA;
      out[orow + 5 * WC] = oB;
    }
  }
}

extern "C" void kernel_launch(void* const* d_in, const int* in_sizes, int n_in,
                              void* d_out, int out_size, void* d_ws, size_t ws_size,
                              hipStream_t stream) {
  const float* x = (const float*)d_in[0];
  float* out = (float*)d_out;
  int total_threads = N_INT + N_BND;        // 304128 = 4752 * 64 exactly
  int grid = total_threads / BLOCK;         // 4752
  median5x5_kernel<<<grid, BLOCK, 0, stream>>>(x, out);
}